// Round 12
// baseline (834.349 us; speedup 1.0000x reference)
//
#include <hip/hip_runtime.h>
#include <hip/hip_bf16.h>
#include <math.h>

#define SHIFT_ 4

typedef __attribute__((ext_vector_type(8))) short bh8;
typedef __attribute__((ext_vector_type(4))) short sh4;
typedef __attribute__((ext_vector_type(4))) float f4;
typedef __attribute__((ext_vector_type(8))) __bf16 bf8t;

static __device__ __forceinline__ f4 mfma16(bh8 a, bh8 b, f4 c){
  return __builtin_amdgcn_mfma_f32_16x16x32_bf16(
    __builtin_bit_cast(bf8t, a), __builtin_bit_cast(bf8t, b), c, 0, 0, 0);
}
static __device__ __forceinline__ unsigned short f2b(float f){
  unsigned u = __builtin_bit_cast(unsigned, f);
  u += 0x7fffu + ((u >> 16) & 1u);
  return (unsigned short)(u >> 16);
}
static __device__ __forceinline__ float b2f(unsigned short h){
  return __builtin_bit_cast(float, ((unsigned)h) << 16);
}
static __device__ __forceinline__ unsigned cvt_pk_bf16(float lo, float hi){
  unsigned r;
  asm("v_cvt_pk_bf16_f32 %0, %1, %2" : "=v"(r) : "v"(lo), "v"(hi));
  return r;
}
static __device__ __forceinline__ float gelu_f(float hv){
  float u = hv * (1.5957691216f + 0.0713548162f * hv * hv);
  return hv * __builtin_amdgcn_rcpf(1.f + __expf(-u));
}
static __device__ __forceinline__ void glds16(const unsigned short* g, unsigned short* l){
  __builtin_amdgcn_global_load_lds(
    (const __attribute__((address_space(1))) unsigned int*)g,
    (__attribute__((address_space(3))) unsigned int*)l, 16, 0, 0);
}

// ---------------- kernel 0: weights f32 -> bf16 (qw pre-scaled by d^-0.5) ---
__global__ __launch_bounds__(256) void prep_w(
    const float* __restrict__ qw, const float* __restrict__ kvw,
    const float* __restrict__ pw, const float* __restrict__ w1,
    const float* __restrict__ w2, unsigned short* __restrict__ wb){
  int i = blockIdx.x * 256 + threadIdx.x;   // 786432 total
  float v;
  if      (i < 65536)  v = qw[i] * 0.17677669529663687f;
  else if (i < 196608) v = kvw[i - 65536];
  else if (i < 262144) v = pw[i - 196608];
  else if (i < 524288) v = w1[i - 262144];
  else                 v = w2[i - 524288];
  wb[i] = f2b(v);
}

// ---------------- kernel 1: LN1 + roll(-4,-4) + window partition ------------
__global__ __launch_bounds__(256) void ln1_win(
    const float* __restrict__ x, const float* __restrict__ g1,
    const float* __restrict__ b1,
    unsigned short* __restrict__ q_in, unsigned short* __restrict__ kv_in){
  int rid  = blockIdx.x * 4 + (threadIdx.x >> 6);   // 0..262143
  int lane = threadIdx.x & 63;
  int d    = rid >> 17;
  int rem  = rid & 131071;          // w*64 + n
  int w = rem >> 6, n = rem & 63;
  int b = w >> 10, hb = (w >> 5) & 31, wbk = w & 31;
  int sh = (hb * 8 + (n >> 3) + SHIFT_) & 255;
  int sw = (wbk * 8 + (n & 7) + SHIFT_) & 255;
  const float* src = x + ((((size_t)(b * 2 + d)) * 256 + sh) * 256 + sw) * 256;
  float4 v = *(const float4*)(src + lane * 4);
  float s  = v.x + v.y + v.z + v.w;
  float ss = v.x * v.x + v.y * v.y + v.z * v.z + v.w * v.w;
  #pragma unroll
  for (int off = 1; off < 64; off <<= 1){ s += __shfl_xor(s, off); ss += __shfl_xor(ss, off); }
  float m    = s * (1.f / 256.f);
  float rstd = rsqrtf(ss * (1.f / 256.f) - m * m + 1e-5f);
  int c = lane * 4;
  float4 g  = *(const float4*)(g1 + c);
  float4 bb = *(const float4*)(b1 + c);
  sh4 o;
  o.x = (short)f2b((v.x - m) * rstd * g.x + bb.x);
  o.y = (short)f2b((v.y - m) * rstd * g.y + bb.y);
  o.z = (short)f2b((v.z - m) * rstd * g.z + bb.z);
  o.w = (short)f2b((v.w - m) * rstd * g.w + bb.w);
  unsigned short* dst = (d == 0 ? q_in : kv_in) + (size_t)rem * 256 + c;
  *(sh4*)dst = o;
}

// ---------------- QKV/P GEMM: 256 thr, 128x128 tiles, 2-phase dbuf ----------
// Linear tile loop tt = nt*4 + t keeps the prefetch pipeline full across
// n-tiles. STAGE(tt+1) issued BEFORE MFMA(tt); one __syncthreads per tile
// (its vmcnt(0) drains a prefetch that flew during the MFMA phase).
template<int MODE, int NT>
__global__ __launch_bounds__(256, 2) void gemm_bt(
    const unsigned short* __restrict__ A, const unsigned short* __restrict__ Wt,
    const float* __restrict__ bias, float bias_scale,
    unsigned short* __restrict__ outb, unsigned short* __restrict__ vpl,
    float* __restrict__ outf, const unsigned short* __restrict__ qin,
    const float* __restrict__ xsrc){
  __shared__ unsigned short sA[2][128][64];
  __shared__ unsigned short sB[2][128][64];
  int m0 = blockIdx.x * 128;
  int tid = threadIdx.x, lane = tid & 63, wid = tid >> 6;   // 4 waves, 2m x 2n
  int wm = wid >> 1, wn = wid & 1;
  int llo = lane & 15, lhi = lane >> 4;
  int lr = lane >> 3, lc = (lane & 7) * 8;
  const int TT = NT * 4;
  // prologue: tile 0 -> buf 0
  #pragma unroll
  for (int c = 0; c < 4; c++){
    int rr = wid * 32 + c * 8;
    glds16(A  + (size_t)(m0 + rr + lr) * 256 + lc, &sA[0][rr][0]);
    glds16(Wt + (size_t)(rr + lr) * 256 + lc,      &sB[0][rr][0]);
  }
  __syncthreads();
  const f4 FZ = {0.f, 0.f, 0.f, 0.f};
  f4 acc[4][4];
  for (int i = 0; i < 4; i++) for (int j = 0; j < 4; j++) acc[i][j] = FZ;
  for (int tt = 0; tt < TT; ++tt){
    int cur = tt & 1;
    if (tt + 1 < TT){
      int t1 = (tt + 1) & 3, n1 = (tt + 1) >> 2;
      #pragma unroll
      for (int c = 0; c < 4; c++){
        int rr = wid * 32 + c * 8;
        glds16(A  + (size_t)(m0 + rr + lr) * 256 + t1 * 64 + lc,       &sA[cur ^ 1][rr][0]);
        glds16(Wt + (size_t)(n1 * 128 + rr + lr) * 256 + t1 * 64 + lc, &sB[cur ^ 1][rr][0]);
      }
    }
    #pragma unroll
    for (int ks = 0; ks < 2; ks++){
      bh8 a[4], b[4];
      #pragma unroll
      for (int mi = 0; mi < 4; mi++) a[mi] = *(const bh8*)&sA[cur][wm * 64 + mi * 16 + llo][ks * 32 + lhi * 8];
      #pragma unroll
      for (int nj = 0; nj < 4; nj++) b[nj] = *(const bh8*)&sB[cur][wn * 64 + nj * 16 + llo][ks * 32 + lhi * 8];
      #pragma unroll
      for (int mi = 0; mi < 4; mi++)
        #pragma unroll
        for (int nj = 0; nj < 4; nj++){
          if (MODE < 2) acc[mi][nj] = mfma16(b[nj], a[mi], acc[mi][nj]);   // swapped
          else          acc[mi][nj] = mfma16(a[mi], b[nj], acc[mi][nj]);
        }
    }
    if ((tt & 3) == 3){
      int nt = tt >> 2;
      if (MODE < 2){
        #pragma unroll
        for (int nj = 0; nj < 4; nj++){
          int cb = wn * 64 + nj * 16 + lhi * 4;
          int col = nt * 128 + cb;
          float4 bv = *(const float4*)(bias + col);
          #pragma unroll
          for (int mi = 0; mi < 4; mi++){
            int row = m0 + wm * 64 + mi * 16 + llo;
            float f0 = acc[mi][nj][0] + bv.x * bias_scale;
            float f1 = acc[mi][nj][1] + bv.y * bias_scale;
            float f2 = acc[mi][nj][2] + bv.z * bias_scale;
            float f3 = acc[mi][nj][3] + bv.w * bias_scale;
            uint2 p;
            p.x = cvt_pk_bf16(f0, f1);
            p.y = cvt_pk_bf16(f2, f3);
            if (MODE == 0 || col < 256) *(uint2*)(outb + (size_t)row * 256 + col) = p;
            else                        *(uint2*)(vpl  + (size_t)row * 256 + (col - 256)) = p;
          }
        }
      } else {
        #pragma unroll
        for (int mi = 0; mi < 4; mi++)
          #pragma unroll
          for (int nj = 0; nj < 4; nj++){
            int col = nt * 128 + wn * 64 + nj * 16 + llo;
            float bv = bias[col] * bias_scale;
            #pragma unroll
            for (int r = 0; r < 4; r++){
              int row = m0 + wm * 64 + mi * 16 + lhi * 4 + r;
              int w = row >> 6, n = row & 63;
              int b = w >> 10, hb = (w >> 5) & 31, wbk = w & 31;
              int hh = (hb * 8 + (n >> 3) + SHIFT_) & 255;
              int ww = (wbk * 8 + (n & 7) + SHIFT_) & 255;
              float res = b2f(qin[(size_t)row * 256 + col]);
              float sc  = xsrc[((((size_t)(b * 2)) * 256 + hh) * 256 + ww) * 256 + col];
              outf[(((size_t)b * 256 + hh) * 256 + ww) * 256 + col] = acc[mi][nj][r] + bv + res + sc;
            }
          }
      }
      for (int i = 0; i < 4; i++) for (int j = 0; j < 4; j++) acc[i][j] = FZ;
    }
    __syncthreads();
  }
}

// ---------------- kernel 3: attention, block = (window, 4-head group) -------
__global__ __launch_bounds__(256, 2) void attn_k(
    const unsigned short* __restrict__ q, const unsigned short* __restrict__ k,
    const unsigned short* __restrict__ v, const float* __restrict__ mask,
    const float* __restrict__ bias_table, unsigned short* __restrict__ aout){
  __shared__ unsigned short sMask[64][72];   // bf16 mask
  __shared__ unsigned short sVT[128][72];    // V^T (d-local x n) for this group
  __shared__ unsigned short sP[4][64][72];
  __shared__ float sBias[4][225];
  int bid = blockIdx.x;                      // 4096 = 2048 windows x 2 groups
  int w = bid >> 1, hg = bid & 1;
  int tid = threadIdx.x, lane = tid & 63, wid = tid >> 6;
  int hd = hg * 4 + wid;
  int llo = lane & 15, lhi = lane >> 4;
  const unsigned short* qp = q + (size_t)w * 64 * 256 + hd * 32;
  const unsigned short* kp = k + (size_t)w * 64 * 256 + hd * 32;
  bh8 af[4], bf[4];
  #pragma unroll
  for (int mi = 0; mi < 4; mi++) af[mi] = *(const bh8*)(qp + (size_t)(mi * 16 + llo) * 256 + lhi * 8);
  #pragma unroll
  for (int nj = 0; nj < 4; nj++) bf[nj] = *(const bh8*)(kp + (size_t)(nj * 16 + llo) * 256 + lhi * 8);
  const float* mrow = mask + (size_t)(w & 1023) * 4096;
  #pragma unroll
  for (int i = 0; i < 2; i++){
    int base = (tid + i * 256) * 8;          // 0..4088
    float4 u0 = *(const float4*)(mrow + base);
    float4 u1 = *(const float4*)(mrow + base + 4);
    int rr = base >> 6, cc = base & 63;
    uint4 p;
    p.x = cvt_pk_bf16(u0.x, u0.y); p.y = cvt_pk_bf16(u0.z, u0.w);
    p.z = cvt_pk_bf16(u1.x, u1.y); p.w = cvt_pk_bf16(u1.z, u1.w);
    *(uint4*)&sMask[rr][cc] = p;
  }
  {
    const unsigned short* vp = v + (size_t)w * 64 * 256 + hg * 128;
    #pragma unroll
    for (int it = 0; it < 4; it++){
      int idx = tid + it * 256;              // 0..1023
      int n = idx >> 4, dc = (idx & 15) * 8;
      bh8 vv = *(const bh8*)(vp + (size_t)n * 256 + dc);
      #pragma unroll
      for (int j = 0; j < 8; j++) sVT[dc + j][n] = (unsigned short)vv[j];
    }
  }
  for (int i = lane; i < 225; i += 64) sBias[wid][i] = bias_table[i * 8 + hd];
  const f4 FZ = {0.f, 0.f, 0.f, 0.f};
  f4 acc[4][4];
  #pragma unroll
  for (int mi = 0; mi < 4; mi++)
    #pragma unroll
    for (int nj = 0; nj < 4; nj++)
      acc[mi][nj] = mfma16(af[mi], bf[nj], FZ);
  __syncthreads();   // sMask + sVT ready
  #pragma unroll
  for (int mi = 0; mi < 4; mi++){
    #pragma unroll
    for (int r = 0; r < 4; r++){
      int rr = mi * 16 + lhi * 4 + r;
      int yi = rr >> 3, xi = rr & 7;
      float sv[4]; float mx = -1e30f;
      #pragma unroll
      for (int nj = 0; nj < 4; nj++){
        int cc = nj * 16 + llo;
        int idx = (yi - (cc >> 3) + 7) * 15 + (xi - (cc & 7) + 7);
        sv[nj] = acc[mi][nj][r] + sBias[wid][idx] + b2f(sMask[rr][cc]);
        mx = fmaxf(mx, sv[nj]);
      }
      #pragma unroll
      for (int off = 1; off < 16; off <<= 1) mx = fmaxf(mx, __shfl_xor(mx, off));
      float sum = 0.f;
      #pragma unroll
      for (int nj = 0; nj < 4; nj++){ sv[nj] = __expf(sv[nj] - mx); sum += sv[nj]; }
      #pragma unroll
      for (int off = 1; off < 16; off <<= 1) sum += __shfl_xor(sum, off);
      float inv = __builtin_amdgcn_rcpf(sum);
      #pragma unroll
      for (int nj = 0; nj < 4; nj++) sP[wid][rr][nj * 16 + llo] = f2b(sv[nj] * inv);
    }
  }
  f4 o[4][2];
  for (int mi = 0; mi < 4; mi++) for (int dj = 0; dj < 2; dj++) o[mi][dj] = FZ;
  #pragma unroll
  for (int ks = 0; ks < 2; ks++){
    bh8 pa[4], vb[2];
    #pragma unroll
    for (int mi = 0; mi < 4; mi++) pa[mi] = *(const bh8*)&sP[wid][mi * 16 + llo][ks * 32 + lhi * 8];
    #pragma unroll
    for (int dj = 0; dj < 2; dj++) vb[dj] = *(const bh8*)&sVT[wid * 32 + dj * 16 + llo][ks * 32 + lhi * 8];
    #pragma unroll
    for (int mi = 0; mi < 4; mi++)
      #pragma unroll
      for (int dj = 0; dj < 2; dj++)
        o[mi][dj] = mfma16(pa[mi], vb[dj], o[mi][dj]);
  }
  #pragma unroll
  for (int mi = 0; mi < 4; mi++)
    for (int dj = 0; dj < 2; dj++)
      for (int r = 0; r < 4; r++){
        int rr = mi * 16 + lhi * 4 + r, dd = dj * 16 + llo;
        aout[((size_t)w * 64 + rr) * 256 + hd * 32 + dd] = f2b(o[mi][dj][r]);
      }
}

// ---------------- kernel 4: LN2 -> bf16 xn (row-major) ----------------------
__global__ __launch_bounds__(256) void ln2_k(
    const float* __restrict__ x1, const float* __restrict__ g2,
    const float* __restrict__ b2, unsigned short* __restrict__ xn){
  int rid  = blockIdx.x * 4 + (threadIdx.x >> 6);   // 0..131071
  int lane = threadIdx.x & 63;
  const float* xr = x1 + (size_t)rid * 256;
  float4 v = *(const float4*)(xr + lane * 4);
  float s  = v.x + v.y + v.z + v.w;
  float ss = v.x * v.x + v.y * v.y + v.z * v.z + v.w * v.w;
  #pragma unroll
  for (int off = 1; off < 64; off <<= 1){ s += __shfl_xor(s, off); ss += __shfl_xor(ss, off); }
  float m    = s * (1.f / 256.f);
  float rstd = rsqrtf(ss * (1.f / 256.f) - m * m + 1e-5f);
  int c = lane * 4;
  float4 g  = *(const float4*)(g2 + c);
  float4 bb = *(const float4*)(b2 + c);
  sh4 o;
  o.x = (short)f2b((v.x - m) * rstd * g.x + bb.x);
  o.y = (short)f2b((v.y - m) * rstd * g.y + bb.y);
  o.z = (short)f2b((v.z - m) * rstd * g.z + bb.z);
  o.w = (short)f2b((v.w - m) * rstd * g.w + bb.w);
  *(sh4*)(xn + (size_t)rid * 256 + c) = o;
}

// ---------------- kernel 5: MLP GEMM, 2-phase dbuf --------------------------
template<int KSTEPS, int EPI, int BIASF>
__global__ __launch_bounds__(256, 2) void mlp_gemm(
    const unsigned short* __restrict__ A, int lda,
    const unsigned short* __restrict__ Bw, int ldb,
    const float* __restrict__ bias,
    unsigned short* __restrict__ outb, int ldo,
    float* __restrict__ outf){
  __shared__ unsigned short sA[2][128][64];
  __shared__ unsigned short sB[2][128][64];
  int n0 = blockIdx.x * 128, m0 = blockIdx.y * 128;
  int tid = threadIdx.x, lane = tid & 63, wid = tid >> 6;
  int wm = wid >> 1, wn = wid & 1;
  int llo = lane & 15, lhi = lane >> 4;
  int lr = lane >> 3, lc = (lane & 7) * 8;
  // prologue
  #pragma unroll
  for (int c = 0; c < 4; c++){
    int rr = wid * 32 + c * 8;
    glds16(A  + (size_t)(m0 + rr + lr) * lda + lc, &sA[0][rr][0]);
    glds16(Bw + (size_t)(n0 + rr + lr) * ldb + lc, &sB[0][rr][0]);
  }
  __syncthreads();
  const f4 FZ = {0.f, 0.f, 0.f, 0.f};
  f4 acc[4][4];
  for (int i = 0; i < 4; i++) for (int j = 0; j < 4; j++) acc[i][j] = FZ;

  for (int t = 0; t < KSTEPS; t++){
    int cur = t & 1;
    if (t + 1 < KSTEPS){
      int k1 = (t + 1) * 64;
      #pragma unroll
      for (int c = 0; c < 4; c++){
        int rr = wid * 32 + c * 8;
        glds16(A  + (size_t)(m0 + rr + lr) * lda + k1 + lc, &sA[cur ^ 1][rr][0]);
        glds16(Bw + (size_t)(n0 + rr + lr) * ldb + k1 + lc, &sB[cur ^ 1][rr][0]);
      }
    }
    #pragma unroll
    for (int ks = 0; ks < 2; ks++){
      bh8 a[4], b[4];
      #pragma unroll
      for (int mi = 0; mi < 4; mi++) a[mi] = *(const bh8*)&sA[cur][wm * 64 + mi * 16 + llo][ks * 32 + lhi * 8];
      #pragma unroll
      for (int nj = 0; nj < 4; nj++) b[nj] = *(const bh8*)&sB[cur][wn * 64 + nj * 16 + llo][ks * 32 + lhi * 8];
      #pragma unroll
      for (int mi = 0; mi < 4; mi++)
        #pragma unroll
        for (int nj = 0; nj < 4; nj++){
          if (EPI == 0) acc[mi][nj] = mfma16(b[nj], a[mi], acc[mi][nj]);   // swapped
          else          acc[mi][nj] = mfma16(a[mi], b[nj], acc[mi][nj]);
        }
    }
    __syncthreads();
  }
  if (EPI == 0){
    #pragma unroll
    for (int nj = 0; nj < 4; nj++){
      int cb = n0 + wn * 64 + nj * 16 + lhi * 4;
      float4 bv = *(const float4*)(bias + cb);
      #pragma unroll
      for (int mi = 0; mi < 4; mi++){
        int row = m0 + wm * 64 + mi * 16 + llo;
        float g0 = gelu_f(acc[mi][nj][0] + bv.x);
        float g1 = gelu_f(acc[mi][nj][1] + bv.y);
        float g2 = gelu_f(acc[mi][nj][2] + bv.z);
        float g3 = gelu_f(acc[mi][nj][3] + bv.w);
        uint2 p;
        p.x = cvt_pk_bf16(g0, g1);
        p.y = cvt_pk_bf16(g2, g3);
        *(uint2*)(outb + (size_t)row * ldo + cb) = p;
      }
    }
  } else {
    #pragma unroll
    for (int mi = 0; mi < 4; mi++)
      #pragma unroll
      for (int nj = 0; nj < 4; nj++){
        int col = n0 + wn * 64 + nj * 16 + llo;
        float bv = BIASF ? bias[col] : 0.f;
        #pragma unroll
        for (int r = 0; r < 4; r++){
          int row = m0 + wm * 64 + mi * 16 + lhi * 4 + r;
          outf[(size_t)row * 256 + col] += acc[mi][nj][r] + bv;
        }
      }
  }
}

extern "C" void kernel_launch(void* const* d_in, const int* in_sizes, int n_in,
                              void* d_out, int out_size, void* d_ws, size_t ws_size,
                              hipStream_t stream){
  const float* x          = (const float*)d_in[0];
  const float* mask       = (const float*)d_in[1];
  const float* g1         = (const float*)d_in[2];
  const float* b1         = (const float*)d_in[3];
  const float* qw         = (const float*)d_in[4];
  const float* qb         = (const float*)d_in[5];
  const float* kvw        = (const float*)d_in[6];
  const float* kvb        = (const float*)d_in[7];
  const float* pw         = (const float*)d_in[8];
  const float* pb         = (const float*)d_in[9];
  const float* bias_table = (const float*)d_in[10];
  const float* g2         = (const float*)d_in[11];
  const float* b2         = (const float*)d_in[12];
  const float* w1         = (const float*)d_in[13];
  const float* bi1        = (const float*)d_in[14];
  const float* w2         = (const float*)d_in[15];
  const float* bi2        = (const float*)d_in[16];
  float* out = (float*)d_out;
  char* ws = (char*)d_ws;
  const long long MB = 1048576LL;
  unsigned short* wb    = (unsigned short*)(ws);
  unsigned short* q_in  = (unsigned short*)(ws + (long long)(1.5 * MB));
  unsigned short* kv_in = (unsigned short*)(ws + (long long)(65.5 * MB));
  unsigned short* qbuf  = (unsigned short*)(ws + (long long)(129.5 * MB));
  unsigned short* kbuf  = (unsigned short*)(ws + (long long)(193.5 * MB));
  unsigned short* vbuf  = (unsigned short*)(ws + (long long)(257.5 * MB));
  unsigned short* aoutb = kv_in;      // kv_in dead after kv GEMM -> alias
  unsigned short* xn    = vbuf;       // vbuf dead after attn_k -> alias
  unsigned short* Hh    = q_in;       // dead after gemm<2> -> alias (67MB/slice)

  prep_w<<<3072, 256, 0, stream>>>(qw, kvw, pw, w1, w2, wb);
  ln1_win<<<65536, 256, 0, stream>>>(x, g1, b1, q_in, kv_in);
  gemm_bt<0, 2><<<1024, 256, 0, stream>>>(q_in, wb, qb, 0.17677669529663687f,
                                          qbuf, nullptr, nullptr, nullptr, nullptr);
  gemm_bt<1, 4><<<1024, 256, 0, stream>>>(kv_in, wb + 65536, kvb, 1.0f,
                                          kbuf, vbuf, nullptr, nullptr, nullptr);
  attn_k<<<4096, 256, 0, stream>>>(qbuf, kbuf, vbuf, mask, bias_table, aoutb);
  gemm_bt<2, 2><<<1024, 256, 0, stream>>>(aoutb, wb + 196608, pb, 1.0f,
                                          nullptr, nullptr, out, q_in, x);
  ln2_k<<<32768, 256, 0, stream>>>(out, g2, b2, xn);
  const unsigned short* w1b = wb + 262144;
  const unsigned short* w2b = wb + 524288;
  // M-sliced MLP (4 slices; H slice = 67MB, L3-resident)
  for (int h = 0; h < 4; h++){
    const long long R = (long long)h * 32768;
    mlp_gemm<4, 0, 0><<<dim3(8, 256), 256, 0, stream>>>(xn + R * 256, 256, w1b, 256,
                                                        bi1, Hh, 1024, nullptr);
    mlp_gemm<16, 1, 1><<<dim3(2, 256), 256, 0, stream>>>(Hh, 1024, w2b, 1024,
                                                         bi2, nullptr, 0, out + R * 256);
  }
}